// Round 9
// baseline (3722.768 us; speedup 1.0000x reference)
//
#include <hip/hip_runtime.h>
#include <hip/hip_bf16.h>
#include <stdint.h>

#define T_N 8192
#define K_N 1024
#define D_N 1024
#define LMBDA 5.0f
#define BIGF 3.0e38f
#define CMAX 32
#define THR 26.0f      // 2*lambda + 4 bound + >10 ulp slack
#define CARRYTHR 13.0f // lambda + 8

// ---------------- norms: numpy-pairwise-exact sum of squares per row ----------------
__global__ __launch_bounds__(256) void k_norms(const float* __restrict__ F,
                                               const float* __restrict__ C,
                                               float* __restrict__ sf2,
                                               float* __restrict__ sc2) {
#pragma clang fp contract(off)
  int wave = threadIdx.x >> 6;
  int lane = threadIdx.x & 63;
  int row = blockIdx.x * 4 + wave;
  const float* src;
  float* dst;
  if (row < T_N) { src = F + (size_t)row * D_N; dst = sf2 + row; }
  else           { src = C + (size_t)(row - T_N) * D_N; dst = sc2 + (row - T_N); }
  int leaf = lane >> 3, j = lane & 7;
  const float* p = src + leaf * 128 + j;
  float x = p[0];
  float r = x * x;
#pragma unroll
  for (int i = 1; i < 16; ++i) {
    float y = p[8 * i];
    r = r + y * y;
  }
  r = r + __shfl_xor(r, 1, 64);
  r = r + __shfl_xor(r, 2, 64);
  r = r + __shfl_xor(r, 4, 64);
  r = r + __shfl_xor(r, 8, 64);
  r = r + __shfl_xor(r, 16, 64);
  r = r + __shfl_xor(r, 32, 64);
  if (lane == 0) *dst = r;
}

// ---------------- d2 GEMM: OpenBLAS-faithful f32 (numerics frozen — do not reorder) ----------------
__global__ __launch_bounds__(256) void k_gemm(const float* __restrict__ F,
                                              const float* __restrict__ C,
                                              const float* __restrict__ sf2,
                                              const float* __restrict__ sc2,
                                              float* __restrict__ d2) {
  __shared__ float As[32][68];
  __shared__ float Bs[32][68];
  int t0 = (int)(blockIdx.x >> 4) * 64;
  int k0 = (int)(blockIdx.x & 15) * 64;
  int tid = threadIdx.x;
  int tx = tid & 15, ty = tid >> 4;
  float acc[4][4], p0[4][4], p1[4][4];
#pragma unroll
  for (int i = 0; i < 4; ++i)
#pragma unroll
    for (int j = 0; j < 4; ++j) { acc[i][j] = 0.0f; p0[i][j] = 0.0f; p1[i][j] = 0.0f; }
  int r = tid & 63;
  int cbase = (tid >> 6) * 2;
  for (int d0 = 0; d0 < D_N; d0 += 32) {
    __syncthreads();
#pragma unroll
    for (int p = 0; p < 2; ++p) {
      int c4 = cbase + p;
      float4 va = *(const float4*)&F[(size_t)(t0 + r) * D_N + d0 + c4 * 4];
      As[c4 * 4 + 0][r] = va.x; As[c4 * 4 + 1][r] = va.y;
      As[c4 * 4 + 2][r] = va.z; As[c4 * 4 + 3][r] = va.w;
      float4 vb = *(const float4*)&C[(size_t)(k0 + r) * D_N + d0 + c4 * 4];
      Bs[c4 * 4 + 0][r] = vb.x; Bs[c4 * 4 + 1][r] = vb.y;
      Bs[c4 * 4 + 2][r] = vb.z; Bs[c4 * 4 + 3][r] = vb.w;
    }
    __syncthreads();
#pragma unroll
    for (int d = 0; d < 32; ++d) {
      float4 a = *(const float4*)&As[d][ty * 4];
      float4 b = *(const float4*)&Bs[d][tx * 4];
      acc[0][0] = fmaf(a.x, b.x, acc[0][0]); acc[0][1] = fmaf(a.x, b.y, acc[0][1]);
      acc[0][2] = fmaf(a.x, b.z, acc[0][2]); acc[0][3] = fmaf(a.x, b.w, acc[0][3]);
      acc[1][0] = fmaf(a.y, b.x, acc[1][0]); acc[1][1] = fmaf(a.y, b.y, acc[1][1]);
      acc[1][2] = fmaf(a.y, b.z, acc[1][2]); acc[1][3] = fmaf(a.y, b.w, acc[1][3]);
      acc[2][0] = fmaf(a.z, b.x, acc[2][0]); acc[2][1] = fmaf(a.z, b.y, acc[2][1]);
      acc[2][2] = fmaf(a.z, b.z, acc[2][2]); acc[2][3] = fmaf(a.z, b.w, acc[2][3]);
      acc[3][0] = fmaf(a.w, b.x, acc[3][0]); acc[3][1] = fmaf(a.w, b.y, acc[3][1]);
      acc[3][2] = fmaf(a.w, b.z, acc[3][2]); acc[3][3] = fmaf(a.w, b.w, acc[3][3]);
    }
    if (d0 == 352) {
#pragma unroll
      for (int i = 0; i < 4; ++i)
#pragma unroll
        for (int j = 0; j < 4; ++j) { p0[i][j] = acc[i][j]; acc[i][j] = 0.0f; }
    }
    if (d0 == 736) {
#pragma unroll
      for (int i = 0; i < 4; ++i)
#pragma unroll
        for (int j = 0; j < 4; ++j) { p1[i][j] = acc[i][j]; acc[i][j] = 0.0f; }
    }
  }
  {
#pragma clang fp contract(off)
#pragma unroll
    for (int i = 0; i < 4; ++i) {
      int t = t0 + ty * 4 + i;
      float sa = sf2[t];
      float o[4];
#pragma unroll
      for (int j = 0; j < 4; ++j) {
        float dot = (p0[i][j] + p1[i][j]) + acc[i][j];
        float two = 2.0f * dot;
        o[j] = (sa - two) + sc2[k0 + tx * 4 + j];
      }
      float4 ov; ov.x = o[0]; ov.y = o[1]; ov.z = o[2]; ov.w = o[3];
      *(float4*)&d2[(size_t)t * K_N + k0 + tx * 4] = ov;
    }
  }
}

// ---------------- cand: per row, exact min + candidate list {k: d <= dmin+THR} ----------------
// cand buffer pre-memset to 0xFF => sentinel (k=-1, d=NaN). NaN is ignored by v_min
// (IEEE minNum) and fails all carry/threshold compares.
__global__ __launch_bounds__(256) void k_cand(const float* __restrict__ d2,
                                              int2* __restrict__ cand) {
  int wave = threadIdx.x >> 6;
  int lane = threadIdx.x & 63;
  int row = blockIdx.x * 4 + wave;
  const float4* p = (const float4*)(d2 + (size_t)row * K_N + lane * 16);
  float4 v0 = p[0], v1 = p[1], v2 = p[2], v3 = p[3];
  float m = fminf(fminf(fminf(v0.x, v0.y), fminf(v0.z, v0.w)),
                  fminf(fminf(v1.x, v1.y), fminf(v1.z, v1.w)));
  float n = fminf(fminf(fminf(v2.x, v2.y), fminf(v2.z, v2.w)),
                  fminf(fminf(v3.x, v3.y), fminf(v3.z, v3.w)));
  m = fminf(m, n);
  m = fminf(m, __shfl_xor(m, 1, 64));
  m = fminf(m, __shfl_xor(m, 2, 64));
  m = fminf(m, __shfl_xor(m, 4, 64));
  m = fminf(m, __shfl_xor(m, 8, 64));
  m = fminf(m, __shfl_xor(m, 16, 64));
  m = fminf(m, __shfl_xor(m, 32, 64));
  float thr = m + THR;
  unsigned flags = 0;
#define TESTC(J, VAL) if ((VAL) <= thr) flags |= (1u << (J));
  TESTC(0, v0.x) TESTC(1, v0.y) TESTC(2, v0.z) TESTC(3, v0.w)
  TESTC(4, v1.x) TESTC(5, v1.y) TESTC(6, v1.z) TESTC(7, v1.w)
  TESTC(8, v2.x) TESTC(9, v2.y) TESTC(10, v2.z) TESTC(11, v2.w)
  TESTC(12, v3.x) TESTC(13, v3.y) TESTC(14, v3.z) TESTC(15, v3.w)
#undef TESTC
  int c = __popc(flags);
  // exclusive prefix sum over 64 lanes
  int pre = c;
#pragma unroll
  for (int off = 1; off <= 32; off <<= 1) {
    int t = __shfl_up(pre, off, 64);
    if (lane >= off) pre += t;
  }
  int idx = pre - c;  // exclusive base
  int2* rowp = cand + (size_t)row * CMAX;
  int kb = lane * 16;
#define EMITC(J, VAL)                                                        \
  if (flags & (1u << (J))) {                                                 \
    if (idx < CMAX) rowp[idx] = make_int2(kb + (J), __float_as_int(VAL));    \
    ++idx;                                                                   \
  }
  EMITC(0, v0.x) EMITC(1, v0.y) EMITC(2, v0.z) EMITC(3, v0.w)
  EMITC(4, v1.x) EMITC(5, v1.y) EMITC(6, v1.z) EMITC(7, v1.w)
  EMITC(8, v2.x) EMITC(9, v2.y) EMITC(10, v2.z) EMITC(11, v2.w)
  EMITC(12, v3.x) EMITC(13, v3.y) EMITC(14, v3.z) EMITC(15, v3.w)
#undef EMITC
}

// ---------------- DPP min chain (result valid in lane 63) ----------------
__device__ __forceinline__ float dpp_min_chain(float x) {
  int t;
  t = __builtin_amdgcn_update_dpp(__float_as_int(x), __float_as_int(x), 0x111, 0xF, 0xF, false);
  x = fminf(x, __int_as_float(t));
  t = __builtin_amdgcn_update_dpp(__float_as_int(x), __float_as_int(x), 0x112, 0xF, 0xF, false);
  x = fminf(x, __int_as_float(t));
  t = __builtin_amdgcn_update_dpp(__float_as_int(x), __float_as_int(x), 0x114, 0xF, 0xF, false);
  x = fminf(x, __int_as_float(t));
  t = __builtin_amdgcn_update_dpp(__float_as_int(x), __float_as_int(x), 0x118, 0xF, 0xF, false);
  x = fminf(x, __int_as_float(t));
  t = __builtin_amdgcn_update_dpp(__float_as_int(x), __float_as_int(x), 0x142, 0xF, 0xF, false);
  x = fminf(x, __int_as_float(t));
  t = __builtin_amdgcn_update_dpp(__float_as_int(x), __float_as_int(x), 0x143, 0xF, 0xF, false);
  x = fminf(x, __int_as_float(t));
  return x;
}
__device__ __forceinline__ float rdlane(float x, int l) {
  return __int_as_float(__builtin_amdgcn_readlane(__float_as_int(x), l));
}

// ---------------- pass1: sparse serial alpha chain over candidate lists ----------------
// Exact: every k that can influence alpha_t or extend satisfies d_t[k] <= dmin_t + 2L+4
// (proof: f>=alpha, RN monotone, ulp<=2) => evaluating only S_t (THR=26) plus carried
// chains {f <= alpha+L+8} reproduces alpha bit-identically to the reference.
__global__ __launch_bounds__(64, 1) void k_pass1(const int2* __restrict__ cand,
                                                 float* __restrict__ alphaOut) {
  const int lane = threadIdx.x;
  const int sl = lane & (CMAX - 1);
  const int2* baseP = cand + sl;
  int2 rg[8];
#pragma unroll
  for (int u = 0; u < 8; ++u) rg[u] = baseP[(size_t)u * CMAX];
  float alpha = 0.0f;
  float areg = 0.0f;
  int ck0 = -2, ck1 = -2, ck2 = -2, ck3 = -2, ck4 = -2, ck5 = -2;
  float cf0 = 0, cf1 = 0, cf2 = 0, cf3 = 0, cf4 = 0, cf5 = 0;
  for (int base = 0; base < T_N; base += 8) {
#pragma unroll
    for (int u = 0; u < 8; ++u) {
      int tau = base + u;
      int ki = rg[u].x;
      float di = __int_as_float(rg[u].y);
      // prefetch row tau+8 into slot u
      int pr = tau + 8; if (pr > T_N - 1) pr = T_N - 1;
      rg[u] = baseP[(size_t)pr * CMAX];
      // match carried chains
      float fp = BIGF;
      fp = (ki == ck0) ? cf0 : fp;
      fp = (ki == ck1) ? cf1 : fp;
      fp = (ki == ck2) ? cf2 : fp;
      fp = (ki == ck3) ? cf3 : fp;
      fp = (ki == ck4) ? cf4 : fp;
      fp = (ki == ck5) ? cf5 : fp;
      // exact reference op order: ext = f - L; f = d + min(alpha, ext)
      float ext = fp - LMBDA;          // BIGF - 5 == BIGF (exact) -> mm = alpha for fresh
      float mm = fminf(alpha, ext);
      float f = di + mm;               // NaN for sentinel slots
      f = (lane < CMAX) ? f : BIGF;    // lanes 32-63 duplicate slots: exclude
      // alpha_t = min over candidates (covers global min; proof in header)
      float red = dpp_min_chain(f);
      float anew = rdlane(red, 63);
      // extract carried set {f <= anew + L + 8}
      float cth = anew + CARRYTHR;
      unsigned long long msk = __ballot(f <= cth);
      int l0 = __ffsll(msk) - 1; bool h0 = (msk != 0ull); msk &= msk - 1;
      int l1 = __ffsll(msk) - 1; bool h1 = (msk != 0ull); msk &= msk - 1;
      int l2 = __ffsll(msk) - 1; bool h2 = (msk != 0ull); msk &= msk - 1;
      int l3 = __ffsll(msk) - 1; bool h3 = (msk != 0ull); msk &= msk - 1;
      int l4 = __ffsll(msk) - 1; bool h4 = (msk != 0ull); msk &= msk - 1;
      int l5 = __ffsll(msk) - 1; bool h5 = (msk != 0ull);
      ck0 = h0 ? __builtin_amdgcn_readlane(ki, l0) : -2;
      cf0 = h0 ? rdlane(f, l0) : 0.0f;
      ck1 = h1 ? __builtin_amdgcn_readlane(ki, l1) : -2;
      cf1 = h1 ? rdlane(f, l1) : 0.0f;
      ck2 = h2 ? __builtin_amdgcn_readlane(ki, l2) : -2;
      cf2 = h2 ? rdlane(f, l2) : 0.0f;
      ck3 = h3 ? __builtin_amdgcn_readlane(ki, l3) : -2;
      cf3 = h3 ? rdlane(f, l3) : 0.0f;
      ck4 = h4 ? __builtin_amdgcn_readlane(ki, l4) : -2;
      cf4 = h4 ? rdlane(f, l4) : 0.0f;
      ck5 = h5 ? __builtin_amdgcn_readlane(ki, l5) : -2;
      cf5 = h5 ? rdlane(f, l5) : 0.0f;
      alpha = anew;
      // record alpha, burst store every 64 steps
      areg = ((tau & 63) == lane) ? alpha : areg;
      if ((tau & 63) == 63) alphaOut[(tau & ~63) + lane] = areg;
    }
  }
}

// ---------------- pass2: chunked warm-start replay per k (validated r1 == full-history r2) ----------------
#define CH 512
#define WARM 64
__global__ __launch_bounds__(256) void k_pass2(const float* __restrict__ d2,
                                               const float* __restrict__ AOUT,
                                               unsigned* __restrict__ pack) {
  int kb = blockIdx.x & 3;
  int tc = blockIdx.x >> 2;
  int k = kb * 256 + threadIdx.x;
  int ts = tc * CH;
  int start = ts - WARM; if (start < 0) start = 0;
  int end = ts + CH;
  __shared__ float lal[CH + WARM + 1];
  for (int i = threadIdx.x; i < end - start + 1; i += 256) {
    int idx = start - 1 + i;
    lal[i] = (idx < 0) ? 0.0f : AOUT[idx];
  }
  __syncthreads();
  float f = BIGF;
  unsigned s = 0;
#pragma unroll 4
  for (int tau = start; tau < end; ++tau) {
    float a_in = lal[tau - start];
    float d = d2[(size_t)tau * K_N + k];
    float ext = f - LMBDA;
    if (a_in < ext) s = (unsigned)tau;
    f = d + fminf(a_in, ext);
    if (tau >= ts) {
      float a_out = lal[tau - start + 1];
      if (f == a_out) atomicMin(&pack[tau], ((unsigned)k << 13) | s);
    }
  }
}

// ---------------- backtrack: ballot run-skip serial chase + parallel fill (validated r1) ----------------
__global__ __launch_bounds__(256) void k_backtrack(const unsigned* __restrict__ pack,
                                                   unsigned* __restrict__ unitsWs,
                                                   float* __restrict__ outUnits) {
  __shared__ unsigned lp[T_N];
  __shared__ unsigned long long msk[T_N / 64];
  int tid = threadIdx.x;
  for (int i = tid * 4; i < T_N; i += 1024) {
    *(uint4*)&lp[i] = *(const uint4*)&pack[i];
  }
  __syncthreads();
  if (tid < 64) {
    int lane = tid;
    int cur = T_N;
    for (int B = T_N - 64; B >= 0; B -= 64) {
      unsigned long long marks = 0ull;
      if (cur > B) {
        unsigned pk = lp[B + lane];
        int bv = (int)(pk & 8191u);
        unsigned long long run = __ballot(bv == B + lane);
        while (cur > B) {
          int L = cur - 1 - B;
          unsigned long long below = (L == 63) ? ~0ull : ((1ull << (L + 1)) - 1ull);
          unsigned long long nz = (~run) & below;
          if (nz == 0ull) { marks |= below; cur = B; break; }
          int j = 63 - __builtin_clzll(nz);
          marks |= below & ~((1ull << j) - 1ull);
          int nb = __builtin_amdgcn_readlane(bv, j);
          cur = nb;
          if (cur > B + j) cur = B + j;
        }
      }
      if (lane == 0) msk[B >> 6] = marks;
    }
  }
  __syncthreads();
  for (int p = tid; p < T_N; p += 256) {
    int w = p >> 6;
    unsigned long long m = msk[w] & (~0ull << (p & 63));
    while (m == 0ull) { ++w; m = msk[w]; }
    int idx = (w << 6) + (int)__builtin_ctzll(m);
    unsigned g = (lp[idx] >> 13) & 1023u;
    unitsWs[p] = g;
    outUnits[p] = (float)g;
  }
}

// ---------------- gather: quantized[t] = codebook[units[t]] ----------------
__global__ __launch_bounds__(256) void k_gather(const float* __restrict__ C,
                                                const unsigned* __restrict__ unitsWs,
                                                float* __restrict__ out) {
  int t = blockIdx.x;
  unsigned u = unitsWs[t] & 1023u;
  const float4* src = (const float4*)(C + (size_t)u * D_N);
  float4* dst = (float4*)(out + (size_t)t * D_N);
  dst[threadIdx.x] = src[threadIdx.x];
}

extern "C" void kernel_launch(void* const* d_in, const int* in_sizes, int n_in,
                              void* d_out, int out_size, void* d_ws, size_t ws_size,
                              hipStream_t stream) {
  const float* F = (const float*)d_in[0];
  const float* C = (const float*)d_in[1];
  float* out = (float*)d_out;
  float* d2 = out;                                  // reuse quantized region as d2 scratch
  float* outUnits = out + (size_t)T_N * D_N;
  char* ws = (char*)d_ws;
  float* alphaOut = (float*)(ws);                    // 32 KB
  unsigned* pack = (unsigned*)(ws + (32 << 10));     // 32 KB
  unsigned* unitsWs = (unsigned*)(ws + (64 << 10));  // 32 KB
  float* sf2 = (float*)(ws + (96 << 10));            // 32 KB
  float* sc2 = (float*)(ws + (128 << 10));           // 4 KB
  int2* cand = (int2*)(ws + (1 << 20));              // 2 MB (8192 x 32 x 8B)

  k_norms<<<(T_N + K_N) / 4, 256, 0, stream>>>(F, C, sf2, sc2);
  hipMemsetAsync(pack, 0xFF, T_N * sizeof(unsigned), stream);
  hipMemsetAsync(cand, 0xFF, (size_t)T_N * CMAX * sizeof(int2), stream);
  k_gemm<<<(T_N / 64) * (K_N / 64), 256, 0, stream>>>(F, C, sf2, sc2, d2);
  k_cand<<<T_N / 4, 256, 0, stream>>>(d2, cand);
  k_pass1<<<1, 64, 0, stream>>>(cand, alphaOut);
  k_pass2<<<(T_N / CH) * 4, 256, 0, stream>>>(d2, alphaOut, pack);
  k_backtrack<<<1, 256, 0, stream>>>(pack, unitsWs, outUnits);
  k_gather<<<T_N, 256, 0, stream>>>(C, unitsWs, out);
}

// Round 10
// 1599.327 us; speedup vs baseline: 2.3277x; 2.3277x over previous
//
#include <hip/hip_runtime.h>
#include <hip/hip_bf16.h>
#include <stdint.h>

#define T_N 8192
#define K_N 1024
#define D_N 1024
#define LMBDA 5.0f
#define BIGF 3.0e38f
#define CMAX 32
#define THR 26.0f      // 2*lambda + 4 bound + >10 ulp slack (r9-validated)

// ---------------- norms: numpy-pairwise-exact sum of squares per row ----------------
__global__ __launch_bounds__(256) void k_norms(const float* __restrict__ F,
                                               const float* __restrict__ C,
                                               float* __restrict__ sf2,
                                               float* __restrict__ sc2) {
#pragma clang fp contract(off)
  int wave = threadIdx.x >> 6;
  int lane = threadIdx.x & 63;
  int row = blockIdx.x * 4 + wave;
  const float* src;
  float* dst;
  if (row < T_N) { src = F + (size_t)row * D_N; dst = sf2 + row; }
  else           { src = C + (size_t)(row - T_N) * D_N; dst = sc2 + (row - T_N); }
  int leaf = lane >> 3, j = lane & 7;
  const float* p = src + leaf * 128 + j;
  float x = p[0];
  float r = x * x;
#pragma unroll
  for (int i = 1; i < 16; ++i) {
    float y = p[8 * i];
    r = r + y * y;
  }
  r = r + __shfl_xor(r, 1, 64);
  r = r + __shfl_xor(r, 2, 64);
  r = r + __shfl_xor(r, 4, 64);
  r = r + __shfl_xor(r, 8, 64);
  r = r + __shfl_xor(r, 16, 64);
  r = r + __shfl_xor(r, 32, 64);
  if (lane == 0) *dst = r;
}

// ---------------- d2 GEMM: OpenBLAS-faithful f32 (numerics frozen — do not reorder) ----------------
__global__ __launch_bounds__(256) void k_gemm(const float* __restrict__ F,
                                              const float* __restrict__ C,
                                              const float* __restrict__ sf2,
                                              const float* __restrict__ sc2,
                                              float* __restrict__ d2) {
  __shared__ float As[32][68];
  __shared__ float Bs[32][68];
  int t0 = (int)(blockIdx.x >> 4) * 64;
  int k0 = (int)(blockIdx.x & 15) * 64;
  int tid = threadIdx.x;
  int tx = tid & 15, ty = tid >> 4;
  float acc[4][4], p0[4][4], p1[4][4];
#pragma unroll
  for (int i = 0; i < 4; ++i)
#pragma unroll
    for (int j = 0; j < 4; ++j) { acc[i][j] = 0.0f; p0[i][j] = 0.0f; p1[i][j] = 0.0f; }
  int r = tid & 63;
  int cbase = (tid >> 6) * 2;
  for (int d0 = 0; d0 < D_N; d0 += 32) {
    __syncthreads();
#pragma unroll
    for (int p = 0; p < 2; ++p) {
      int c4 = cbase + p;
      float4 va = *(const float4*)&F[(size_t)(t0 + r) * D_N + d0 + c4 * 4];
      As[c4 * 4 + 0][r] = va.x; As[c4 * 4 + 1][r] = va.y;
      As[c4 * 4 + 2][r] = va.z; As[c4 * 4 + 3][r] = va.w;
      float4 vb = *(const float4*)&C[(size_t)(k0 + r) * D_N + d0 + c4 * 4];
      Bs[c4 * 4 + 0][r] = vb.x; Bs[c4 * 4 + 1][r] = vb.y;
      Bs[c4 * 4 + 2][r] = vb.z; Bs[c4 * 4 + 3][r] = vb.w;
    }
    __syncthreads();
#pragma unroll
    for (int d = 0; d < 32; ++d) {
      float4 a = *(const float4*)&As[d][ty * 4];
      float4 b = *(const float4*)&Bs[d][tx * 4];
      acc[0][0] = fmaf(a.x, b.x, acc[0][0]); acc[0][1] = fmaf(a.x, b.y, acc[0][1]);
      acc[0][2] = fmaf(a.x, b.z, acc[0][2]); acc[0][3] = fmaf(a.x, b.w, acc[0][3]);
      acc[1][0] = fmaf(a.y, b.x, acc[1][0]); acc[1][1] = fmaf(a.y, b.y, acc[1][1]);
      acc[1][2] = fmaf(a.y, b.z, acc[1][2]); acc[1][3] = fmaf(a.y, b.w, acc[1][3]);
      acc[2][0] = fmaf(a.z, b.x, acc[2][0]); acc[2][1] = fmaf(a.z, b.y, acc[2][1]);
      acc[2][2] = fmaf(a.z, b.z, acc[2][2]); acc[2][3] = fmaf(a.z, b.w, acc[2][3]);
      acc[3][0] = fmaf(a.w, b.x, acc[3][0]); acc[3][1] = fmaf(a.w, b.y, acc[3][1]);
      acc[3][2] = fmaf(a.w, b.z, acc[3][2]); acc[3][3] = fmaf(a.w, b.w, acc[3][3]);
    }
    if (d0 == 352) {
#pragma unroll
      for (int i = 0; i < 4; ++i)
#pragma unroll
        for (int j = 0; j < 4; ++j) { p0[i][j] = acc[i][j]; acc[i][j] = 0.0f; }
    }
    if (d0 == 736) {
#pragma unroll
      for (int i = 0; i < 4; ++i)
#pragma unroll
        for (int j = 0; j < 4; ++j) { p1[i][j] = acc[i][j]; acc[i][j] = 0.0f; }
    }
  }
  {
#pragma clang fp contract(off)
#pragma unroll
    for (int i = 0; i < 4; ++i) {
      int t = t0 + ty * 4 + i;
      float sa = sf2[t];
      float o[4];
#pragma unroll
      for (int j = 0; j < 4; ++j) {
        float dot = (p0[i][j] + p1[i][j]) + acc[i][j];
        float two = 2.0f * dot;
        o[j] = (sa - two) + sc2[k0 + tx * 4 + j];
      }
      float4 ov; ov.x = o[0]; ov.y = o[1]; ov.z = o[2]; ov.w = o[3];
      *(float4*)&d2[(size_t)t * K_N + k0 + tx * 4] = ov;
    }
  }
}

// ---------------- cand: per row, candidate list {k: d <= dmin+THR} (r9-validated) ----------------
// cand pre-memset to 0xFF => sentinel (k=-1, d=NaN). NaN ignored by v_min (minNum).
__global__ __launch_bounds__(256) void k_cand(const float* __restrict__ d2,
                                              int2* __restrict__ cand) {
  int wave = threadIdx.x >> 6;
  int lane = threadIdx.x & 63;
  int row = blockIdx.x * 4 + wave;
  const float4* p = (const float4*)(d2 + (size_t)row * K_N + lane * 16);
  float4 v0 = p[0], v1 = p[1], v2 = p[2], v3 = p[3];
  float m = fminf(fminf(fminf(v0.x, v0.y), fminf(v0.z, v0.w)),
                  fminf(fminf(v1.x, v1.y), fminf(v1.z, v1.w)));
  float n = fminf(fminf(fminf(v2.x, v2.y), fminf(v2.z, v2.w)),
                  fminf(fminf(v3.x, v3.y), fminf(v3.z, v3.w)));
  m = fminf(m, n);
  m = fminf(m, __shfl_xor(m, 1, 64));
  m = fminf(m, __shfl_xor(m, 2, 64));
  m = fminf(m, __shfl_xor(m, 4, 64));
  m = fminf(m, __shfl_xor(m, 8, 64));
  m = fminf(m, __shfl_xor(m, 16, 64));
  m = fminf(m, __shfl_xor(m, 32, 64));
  float thr = m + THR;
  unsigned flags = 0;
#define TESTC(J, VAL) if ((VAL) <= thr) flags |= (1u << (J));
  TESTC(0, v0.x) TESTC(1, v0.y) TESTC(2, v0.z) TESTC(3, v0.w)
  TESTC(4, v1.x) TESTC(5, v1.y) TESTC(6, v1.z) TESTC(7, v1.w)
  TESTC(8, v2.x) TESTC(9, v2.y) TESTC(10, v2.z) TESTC(11, v2.w)
  TESTC(12, v3.x) TESTC(13, v3.y) TESTC(14, v3.z) TESTC(15, v3.w)
#undef TESTC
  int c = __popc(flags);
  int pre = c;
#pragma unroll
  for (int off = 1; off <= 32; off <<= 1) {
    int t = __shfl_up(pre, off, 64);
    if (lane >= off) pre += t;
  }
  int idx = pre - c;
  int2* rowp = cand + (size_t)row * CMAX;
  int kb = lane * 16;
#define EMITC(J, VAL)                                                        \
  if (flags & (1u << (J))) {                                                 \
    if (idx < CMAX) rowp[idx] = make_int2(kb + (J), __float_as_int(VAL));    \
    ++idx;                                                                   \
  }
  EMITC(0, v0.x) EMITC(1, v0.y) EMITC(2, v0.z) EMITC(3, v0.w)
  EMITC(4, v1.x) EMITC(5, v1.y) EMITC(6, v1.z) EMITC(7, v1.w)
  EMITC(8, v2.x) EMITC(9, v2.y) EMITC(10, v2.z) EMITC(11, v2.w)
  EMITC(12, v3.x) EMITC(13, v3.y) EMITC(14, v3.z) EMITC(15, v3.w)
#undef EMITC
}

// ---------------- prev: slot-j of row t -> byte-index of same-k slot in row t-1 ----------------
// Output pd[t][j] = (prev_slot*4 or -4, d_bits). Fully parallel over rows.
__global__ __launch_bounds__(256) void k_prev(const int2* __restrict__ cand,
                                              int2* __restrict__ pd) {
  __shared__ int sh[4][32];
  int w = threadIdx.x >> 6;
  int lane = threadIdx.x & 63;
  int row = blockIdx.x * 4 + w;
  if (lane >= 32) {
    int j = lane - 32;
    sh[w][j] = (row > 0) ? cand[(size_t)(row - 1) * CMAX + j].x : -2;
  }
  int2 cur;
  if (lane < 32) cur = cand[(size_t)row * CMAX + lane];
  __syncthreads();
  if (lane < 32) {
    int pp = -4;
#pragma unroll
    for (int i = 0; i < 32; ++i) {
      if (sh[w][i] == cur.x) pp = i * 4;
    }
    pd[(size_t)row * CMAX + lane] = make_int2(pp, cur.y);
  }
}

// ---------------- DPP min over lanes 0-31 (result valid in lane 31; upper half never crosses) --
__device__ __forceinline__ float dpp_min32(float x) {
  int t;
  t = __builtin_amdgcn_update_dpp(__float_as_int(x), __float_as_int(x), 0x111, 0xF, 0xF, false);
  x = fminf(x, __int_as_float(t));
  t = __builtin_amdgcn_update_dpp(__float_as_int(x), __float_as_int(x), 0x112, 0xF, 0xF, false);
  x = fminf(x, __int_as_float(t));
  t = __builtin_amdgcn_update_dpp(__float_as_int(x), __float_as_int(x), 0x114, 0xF, 0xF, false);
  x = fminf(x, __int_as_float(t));
  t = __builtin_amdgcn_update_dpp(__float_as_int(x), __float_as_int(x), 0x118, 0xF, 0xF, false);
  x = fminf(x, __int_as_float(t));
  t = __builtin_amdgcn_update_dpp(__float_as_int(x), __float_as_int(x), 0x142, 0xF, 0xF, false); // row_bcast:15
  x = fminf(x, __int_as_float(t));
  return x;
}
__device__ __forceinline__ float rdlane(float x, int l) {
  return __int_as_float(__builtin_amdgcn_readlane(__float_as_int(x), l));
}

// ---------------- pass1: sparse serial alpha chain, bpermute chain-matching ----------------
// Per step: fp[slot] = fstate[prevptr[slot]] via one ds_bpermute; f = d + min(alpha, fp-L);
// alpha = min over slots. Evaluated-chain set is a superset of r9's (validated THR=26 proof);
// every FP op bit-identical to the reference recurrence.
__global__ __launch_bounds__(64, 1) void k_pass1(const int2* __restrict__ pd,
                                                 float* __restrict__ alphaOut) {
  const int lane = threadIdx.x;
  const int sl = lane & (CMAX - 1);
  const int2* basep = pd + sl;
  int2 rg[8];
#pragma unroll
  for (int u = 0; u < 8; ++u) rg[u] = basep[(size_t)u * CMAX];
  float fstate = BIGF;     // f_{t-1} for my slot (lanes 0-31 meaningful)
  float valpha = 0.0f;     // alpha_{t-1}, wave-uniform
  float areg = 0.0f;
  for (int base = 0; base < T_N; base += 8) {
#pragma unroll
    for (int u = 0; u < 8; ++u) {
      int tau = base + u;
      int ppb = rg[u].x;
      float d = __int_as_float(rg[u].y);
      int pr = tau + 8; if (pr > T_N - 1) pr = T_N - 1;
      rg[u] = basep[(size_t)pr * CMAX];
      // fp = previous-step f of the same k (or BIG if chain is fresh/dead)
      int fpb = __builtin_amdgcn_ds_bpermute(ppb, __float_as_int(fstate));
      float fp = (ppb < 0) ? BIGF : __int_as_float(fpb);
      // exact reference op order: ext = f - L; f = d + min(alpha, ext)
      float ext = fp - LMBDA;
      float mm = fminf(valpha, ext);
      float f = d + mm;            // NaN for sentinel slots (ignored by v_min)
      fstate = f;
      // alpha_t = min over slots 0-31 (argmin-k is always a candidate: exact)
      float red = dpp_min32(f);
      valpha = rdlane(red, 31);
      // record alpha, burst store every 64 steps
      areg = ((tau & 63) == lane) ? valpha : areg;
      if ((tau & 63) == 63) alphaOut[(tau & ~63) + lane] = areg;
    }
  }
}

// ---------------- pass2: chunked warm-start replay per k (validated r1 == full-history r2) ----------------
#define CH 512
#define WARM 64
__global__ __launch_bounds__(256) void k_pass2(const float* __restrict__ d2,
                                               const float* __restrict__ AOUT,
                                               unsigned* __restrict__ pack) {
  int kb = blockIdx.x & 3;
  int tc = blockIdx.x >> 2;
  int k = kb * 256 + threadIdx.x;
  int ts = tc * CH;
  int start = ts - WARM; if (start < 0) start = 0;
  int end = ts + CH;
  __shared__ float lal[CH + WARM + 1];
  for (int i = threadIdx.x; i < end - start + 1; i += 256) {
    int idx = start - 1 + i;
    lal[i] = (idx < 0) ? 0.0f : AOUT[idx];
  }
  __syncthreads();
  float f = BIGF;
  unsigned s = 0;
#pragma unroll 4
  for (int tau = start; tau < end; ++tau) {
    float a_in = lal[tau - start];
    float d = d2[(size_t)tau * K_N + k];
    float ext = f - LMBDA;
    if (a_in < ext) s = (unsigned)tau;
    f = d + fminf(a_in, ext);
    if (tau >= ts) {
      float a_out = lal[tau - start + 1];
      if (f == a_out) atomicMin(&pack[tau], ((unsigned)k << 13) | s);
    }
  }
}

// ---------------- backtrack: ballot run-skip serial chase + parallel fill (validated r1) ----------------
__global__ __launch_bounds__(256) void k_backtrack(const unsigned* __restrict__ pack,
                                                   unsigned* __restrict__ unitsWs,
                                                   float* __restrict__ outUnits) {
  __shared__ unsigned lp[T_N];
  __shared__ unsigned long long msk[T_N / 64];
  int tid = threadIdx.x;
  for (int i = tid * 4; i < T_N; i += 1024) {
    *(uint4*)&lp[i] = *(const uint4*)&pack[i];
  }
  __syncthreads();
  if (tid < 64) {
    int lane = tid;
    int cur = T_N;
    for (int B = T_N - 64; B >= 0; B -= 64) {
      unsigned long long marks = 0ull;
      if (cur > B) {
        unsigned pk = lp[B + lane];
        int bv = (int)(pk & 8191u);
        unsigned long long run = __ballot(bv == B + lane);
        while (cur > B) {
          int L = cur - 1 - B;
          unsigned long long below = (L == 63) ? ~0ull : ((1ull << (L + 1)) - 1ull);
          unsigned long long nz = (~run) & below;
          if (nz == 0ull) { marks |= below; cur = B; break; }
          int j = 63 - __builtin_clzll(nz);
          marks |= below & ~((1ull << j) - 1ull);
          int nb = __builtin_amdgcn_readlane(bv, j);
          cur = nb;
          if (cur > B + j) cur = B + j;
        }
      }
      if (lane == 0) msk[B >> 6] = marks;
    }
  }
  __syncthreads();
  for (int p = tid; p < T_N; p += 256) {
    int w = p >> 6;
    unsigned long long m = msk[w] & (~0ull << (p & 63));
    while (m == 0ull) { ++w; m = msk[w]; }
    int idx = (w << 6) + (int)__builtin_ctzll(m);
    unsigned g = (lp[idx] >> 13) & 1023u;
    unitsWs[p] = g;
    outUnits[p] = (float)g;
  }
}

// ---------------- gather: quantized[t] = codebook[units[t]] ----------------
__global__ __launch_bounds__(256) void k_gather(const float* __restrict__ C,
                                                const unsigned* __restrict__ unitsWs,
                                                float* __restrict__ out) {
  int t = blockIdx.x;
  unsigned u = unitsWs[t] & 1023u;
  const float4* src = (const float4*)(C + (size_t)u * D_N);
  float4* dst = (float4*)(out + (size_t)t * D_N);
  dst[threadIdx.x] = src[threadIdx.x];
}

extern "C" void kernel_launch(void* const* d_in, const int* in_sizes, int n_in,
                              void* d_out, int out_size, void* d_ws, size_t ws_size,
                              hipStream_t stream) {
  const float* F = (const float*)d_in[0];
  const float* C = (const float*)d_in[1];
  float* out = (float*)d_out;
  float* d2 = out;                                  // reuse quantized region as d2 scratch
  float* outUnits = out + (size_t)T_N * D_N;
  char* ws = (char*)d_ws;
  float* alphaOut = (float*)(ws);                    // 32 KB
  unsigned* pack = (unsigned*)(ws + (32 << 10));     // 32 KB
  unsigned* unitsWs = (unsigned*)(ws + (64 << 10));  // 32 KB
  float* sf2 = (float*)(ws + (96 << 10));            // 32 KB
  float* sc2 = (float*)(ws + (128 << 10));           // 4 KB
  int2* cand = (int2*)(ws + (1 << 20));              // 2 MB (8192 x 32 x 8B)
  int2* pd = (int2*)(ws + (3 << 20));                // 2 MB

  k_norms<<<(T_N + K_N) / 4, 256, 0, stream>>>(F, C, sf2, sc2);
  hipMemsetAsync(pack, 0xFF, T_N * sizeof(unsigned), stream);
  hipMemsetAsync(cand, 0xFF, (size_t)T_N * CMAX * sizeof(int2), stream);
  k_gemm<<<(T_N / 64) * (K_N / 64), 256, 0, stream>>>(F, C, sf2, sc2, d2);
  k_cand<<<T_N / 4, 256, 0, stream>>>(d2, cand);
  k_prev<<<T_N / 4, 256, 0, stream>>>(cand, pd);
  k_pass1<<<1, 64, 0, stream>>>(pd, alphaOut);
  k_pass2<<<(T_N / CH) * 4, 256, 0, stream>>>(d2, alphaOut, pack);
  k_backtrack<<<1, 256, 0, stream>>>(pack, unitsWs, outUnits);
  k_gather<<<T_N, 256, 0, stream>>>(C, unitsWs, out);
}

// Round 11
// 1373.098 us; speedup vs baseline: 2.7112x; 1.1648x over previous
//
#include <hip/hip_runtime.h>
#include <hip/hip_bf16.h>
#include <stdint.h>

#define T_N 8192
#define K_N 1024
#define D_N 1024
#define LMBDA 5.0f
#define BIGF 3.0e38f
#define CMAX 32
#define THR 26.0f      // 2*lambda + 4 bound + >10 ulp slack (r9-validated)

// ---------------- norms: numpy-pairwise-exact sum of squares per row ----------------
__global__ __launch_bounds__(256) void k_norms(const float* __restrict__ F,
                                               const float* __restrict__ C,
                                               float* __restrict__ sf2,
                                               float* __restrict__ sc2) {
#pragma clang fp contract(off)
  int wave = threadIdx.x >> 6;
  int lane = threadIdx.x & 63;
  int row = blockIdx.x * 4 + wave;
  const float* src;
  float* dst;
  if (row < T_N) { src = F + (size_t)row * D_N; dst = sf2 + row; }
  else           { src = C + (size_t)(row - T_N) * D_N; dst = sc2 + (row - T_N); }
  int leaf = lane >> 3, j = lane & 7;
  const float* p = src + leaf * 128 + j;
  float x = p[0];
  float r = x * x;
#pragma unroll
  for (int i = 1; i < 16; ++i) {
    float y = p[8 * i];
    r = r + y * y;
  }
  r = r + __shfl_xor(r, 1, 64);
  r = r + __shfl_xor(r, 2, 64);
  r = r + __shfl_xor(r, 4, 64);
  r = r + __shfl_xor(r, 8, 64);
  r = r + __shfl_xor(r, 16, 64);
  r = r + __shfl_xor(r, 32, 64);
  if (lane == 0) *dst = r;
}

// ---------------- d2 GEMM: OpenBLAS-faithful f32 (numerics frozen — do not reorder) ----------------
__global__ __launch_bounds__(256) void k_gemm(const float* __restrict__ F,
                                              const float* __restrict__ C,
                                              const float* __restrict__ sf2,
                                              const float* __restrict__ sc2,
                                              float* __restrict__ d2) {
  __shared__ float As[32][68];
  __shared__ float Bs[32][68];
  int t0 = (int)(blockIdx.x >> 4) * 64;
  int k0 = (int)(blockIdx.x & 15) * 64;
  int tid = threadIdx.x;
  int tx = tid & 15, ty = tid >> 4;
  float acc[4][4], p0[4][4], p1[4][4];
#pragma unroll
  for (int i = 0; i < 4; ++i)
#pragma unroll
    for (int j = 0; j < 4; ++j) { acc[i][j] = 0.0f; p0[i][j] = 0.0f; p1[i][j] = 0.0f; }
  int r = tid & 63;
  int cbase = (tid >> 6) * 2;
  for (int d0 = 0; d0 < D_N; d0 += 32) {
    __syncthreads();
#pragma unroll
    for (int p = 0; p < 2; ++p) {
      int c4 = cbase + p;
      float4 va = *(const float4*)&F[(size_t)(t0 + r) * D_N + d0 + c4 * 4];
      As[c4 * 4 + 0][r] = va.x; As[c4 * 4 + 1][r] = va.y;
      As[c4 * 4 + 2][r] = va.z; As[c4 * 4 + 3][r] = va.w;
      float4 vb = *(const float4*)&C[(size_t)(k0 + r) * D_N + d0 + c4 * 4];
      Bs[c4 * 4 + 0][r] = vb.x; Bs[c4 * 4 + 1][r] = vb.y;
      Bs[c4 * 4 + 2][r] = vb.z; Bs[c4 * 4 + 3][r] = vb.w;
    }
    __syncthreads();
#pragma unroll
    for (int d = 0; d < 32; ++d) {
      float4 a = *(const float4*)&As[d][ty * 4];
      float4 b = *(const float4*)&Bs[d][tx * 4];
      acc[0][0] = fmaf(a.x, b.x, acc[0][0]); acc[0][1] = fmaf(a.x, b.y, acc[0][1]);
      acc[0][2] = fmaf(a.x, b.z, acc[0][2]); acc[0][3] = fmaf(a.x, b.w, acc[0][3]);
      acc[1][0] = fmaf(a.y, b.x, acc[1][0]); acc[1][1] = fmaf(a.y, b.y, acc[1][1]);
      acc[1][2] = fmaf(a.y, b.z, acc[1][2]); acc[1][3] = fmaf(a.y, b.w, acc[1][3]);
      acc[2][0] = fmaf(a.z, b.x, acc[2][0]); acc[2][1] = fmaf(a.z, b.y, acc[2][1]);
      acc[2][2] = fmaf(a.z, b.z, acc[2][2]); acc[2][3] = fmaf(a.z, b.w, acc[2][3]);
      acc[3][0] = fmaf(a.w, b.x, acc[3][0]); acc[3][1] = fmaf(a.w, b.y, acc[3][1]);
      acc[3][2] = fmaf(a.w, b.z, acc[3][2]); acc[3][3] = fmaf(a.w, b.w, acc[3][3]);
    }
    if (d0 == 352) {
#pragma unroll
      for (int i = 0; i < 4; ++i)
#pragma unroll
        for (int j = 0; j < 4; ++j) { p0[i][j] = acc[i][j]; acc[i][j] = 0.0f; }
    }
    if (d0 == 736) {
#pragma unroll
      for (int i = 0; i < 4; ++i)
#pragma unroll
        for (int j = 0; j < 4; ++j) { p1[i][j] = acc[i][j]; acc[i][j] = 0.0f; }
    }
  }
  {
#pragma clang fp contract(off)
#pragma unroll
    for (int i = 0; i < 4; ++i) {
      int t = t0 + ty * 4 + i;
      float sa = sf2[t];
      float o[4];
#pragma unroll
      for (int j = 0; j < 4; ++j) {
        float dot = (p0[i][j] + p1[i][j]) + acc[i][j];
        float two = 2.0f * dot;
        o[j] = (sa - two) + sc2[k0 + tx * 4 + j];
      }
      float4 ov; ov.x = o[0]; ov.y = o[1]; ov.z = o[2]; ov.w = o[3];
      *(float4*)&d2[(size_t)t * K_N + k0 + tx * 4] = ov;
    }
  }
}

// ---------------- cand: per row, candidate list {k: d <= dmin+THR} + row dmin ----------------
// cand pre-memset to 0xFF => sentinel (k=-1, d=NaN). NaN ignored by v_min (minNum).
__global__ __launch_bounds__(256) void k_cand(const float* __restrict__ d2,
                                              int2* __restrict__ cand,
                                              float* __restrict__ dminOut) {
  int wave = threadIdx.x >> 6;
  int lane = threadIdx.x & 63;
  int row = blockIdx.x * 4 + wave;
  const float4* p = (const float4*)(d2 + (size_t)row * K_N + lane * 16);
  float4 v0 = p[0], v1 = p[1], v2 = p[2], v3 = p[3];
  float m = fminf(fminf(fminf(v0.x, v0.y), fminf(v0.z, v0.w)),
                  fminf(fminf(v1.x, v1.y), fminf(v1.z, v1.w)));
  float n = fminf(fminf(fminf(v2.x, v2.y), fminf(v2.z, v2.w)),
                  fminf(fminf(v3.x, v3.y), fminf(v3.z, v3.w)));
  m = fminf(m, n);
  m = fminf(m, __shfl_xor(m, 1, 64));
  m = fminf(m, __shfl_xor(m, 2, 64));
  m = fminf(m, __shfl_xor(m, 4, 64));
  m = fminf(m, __shfl_xor(m, 8, 64));
  m = fminf(m, __shfl_xor(m, 16, 64));
  m = fminf(m, __shfl_xor(m, 32, 64));
  if (lane == 0) dminOut[row] = m;
  float thr = m + THR;
  unsigned flags = 0;
#define TESTC(J, VAL) if ((VAL) <= thr) flags |= (1u << (J));
  TESTC(0, v0.x) TESTC(1, v0.y) TESTC(2, v0.z) TESTC(3, v0.w)
  TESTC(4, v1.x) TESTC(5, v1.y) TESTC(6, v1.z) TESTC(7, v1.w)
  TESTC(8, v2.x) TESTC(9, v2.y) TESTC(10, v2.z) TESTC(11, v2.w)
  TESTC(12, v3.x) TESTC(13, v3.y) TESTC(14, v3.z) TESTC(15, v3.w)
#undef TESTC
  int c = __popc(flags);
  int pre = c;
#pragma unroll
  for (int off = 1; off <= 32; off <<= 1) {
    int t = __shfl_up(pre, off, 64);
    if (lane >= off) pre += t;
  }
  int idx = pre - c;
  int2* rowp = cand + (size_t)row * CMAX;
  int kb = lane * 16;
#define EMITC(J, VAL)                                                        \
  if (flags & (1u << (J))) {                                                 \
    if (idx < CMAX) rowp[idx] = make_int2(kb + (J), __float_as_int(VAL));    \
    ++idx;                                                                   \
  }
  EMITC(0, v0.x) EMITC(1, v0.y) EMITC(2, v0.z) EMITC(3, v0.w)
  EMITC(4, v1.x) EMITC(5, v1.y) EMITC(6, v1.z) EMITC(7, v1.w)
  EMITC(8, v2.x) EMITC(9, v2.y) EMITC(10, v2.z) EMITC(11, v2.w)
  EMITC(12, v3.x) EMITC(13, v3.y) EMITC(14, v3.z) EMITC(15, v3.w)
#undef EMITC
}

// ---------------- prev: slot-j of row t -> byte-index of same-k slot in row t-1 ----------------
__global__ __launch_bounds__(256) void k_prev(const int2* __restrict__ cand,
                                              int2* __restrict__ pd) {
  __shared__ int sh[4][32];
  int w = threadIdx.x >> 6;
  int lane = threadIdx.x & 63;
  int row = blockIdx.x * 4 + w;
  if (lane >= 32) {
    int j = lane - 32;
    sh[w][j] = (row > 0) ? cand[(size_t)(row - 1) * CMAX + j].x : -2;
  }
  int2 cur;
  if (lane < 32) cur = cand[(size_t)row * CMAX + lane];
  __syncthreads();
  if (lane < 32) {
    int pp = -4;
#pragma unroll
    for (int i = 0; i < 32; ++i) {
      if (sh[w][i] == cur.x) pp = i * 4;
    }
    pd[(size_t)row * CMAX + lane] = make_int2(pp, cur.y);
  }
}

// ---------------- DPP min over lanes 0-31 (result valid in lane 31) ----------------
__device__ __forceinline__ float dpp_min32(float x) {
  int t;
  t = __builtin_amdgcn_update_dpp(__float_as_int(x), __float_as_int(x), 0x111, 0xF, 0xF, false);
  x = fminf(x, __int_as_float(t));
  t = __builtin_amdgcn_update_dpp(__float_as_int(x), __float_as_int(x), 0x112, 0xF, 0xF, false);
  x = fminf(x, __int_as_float(t));
  t = __builtin_amdgcn_update_dpp(__float_as_int(x), __float_as_int(x), 0x114, 0xF, 0xF, false);
  x = fminf(x, __int_as_float(t));
  t = __builtin_amdgcn_update_dpp(__float_as_int(x), __float_as_int(x), 0x118, 0xF, 0xF, false);
  x = fminf(x, __int_as_float(t));
  t = __builtin_amdgcn_update_dpp(__float_as_int(x), __float_as_int(x), 0x142, 0xF, 0xF, false); // row_bcast:15
  x = fminf(x, __int_as_float(t));
  return x;
}
__device__ __forceinline__ float rdlane(float x, int l) {
  return __int_as_float(__builtin_amdgcn_readlane(__float_as_int(x), l));
}

// ---------------- pass1: sparse alpha chain, reduce pipelined off the critical path ----------
// r6-validated split + r10-validated slot machinery:
//   pre_t = RN(d_t + RN(f_{t-1}-L))            (alpha-free; bpermute chain match)
//   f_t   = min(pre_t, RN(d_t + a_{t-1}))      (exact == ref f_t)
//   a_t   = min(P_t, RN(dmin_t + a_{t-1})),  P_t = min_slots pre_t  (exact; THR proof)
// P_t's DPP reduce is issued at step t, consumed at step t+1 -> hidden under bpermute.
__global__ __launch_bounds__(64, 1) void k_pass1(const int2* __restrict__ pd,
                                                 const float* __restrict__ dminArr,
                                                 float* __restrict__ alphaOut) {
  const int lane = threadIdx.x;
  const int sl = lane & (CMAX - 1);
  const int2* basep = pd + sl;
  int2 rg[8];
#pragma unroll
  for (int u = 0; u < 8; ++u) rg[u] = basep[(size_t)u * CMAX];
  float fstate = BIGF;     // f_{t-1} for my slot
  float alpha = 0.0f;      // on entry to iter t: a_{t-2}; after finalize: a_{t-1}
  float red = 0.0f;        // pending reduce of pre_{t-1} (init: P_{-1}=0 with dm_prev=0 -> a_{-1}=0)
  float dm_prev = 0.0f;    // dmin_{t-1}
  float areg = 0.0f;
  float dmv_next = dminArr[lane];
  for (int b64 = 0; b64 < T_N; b64 += 64) {
    float dmv = dmv_next;
    int nb = b64 + 64; if (nb >= T_N) nb = 0;
    dmv_next = dminArr[nb + lane];
    for (int b8 = 0; b8 < 64; b8 += 8) {
#pragma unroll
      for (int u = 0; u < 8; ++u) {
        int tau = b64 + b8 + u;
        int ppb = rg[u].x;
        float d = __int_as_float(rg[u].y);
        // issue bpermute early (longest latency)
        int fpb = __builtin_amdgcn_ds_bpermute(ppb, __float_as_int(fstate));
        // prefetch row tau+8
        int pr = tau + 8; if (pr > T_N - 1) pr = T_N - 1;
        rg[u] = basep[(size_t)pr * CMAX];
        // finalize a_{tau-1} = min(P_{tau-1}, dmin_{tau-1} + a_{tau-2})  (overlaps bpermute)
        float P = rdlane(red, 31);
        alpha = fminf(P, dm_prev + alpha);
        // record a_{tau-1}
        if (tau > 0) {
          int pos = tau - 1;
          areg = ((pos & 63) == lane) ? alpha : areg;
          if ((pos & 63) == 63) alphaOut[(pos & ~63) + lane] = areg;
        }
        // pre_t, f_t
        float fp = (ppb < 0) ? BIGF : __int_as_float(fpb);
        float pre = d + (fp - LMBDA);       // NaN for sentinels (ignored by v_min)
        fstate = fminf(pre, d + alpha);     // == ref f_t exactly
        // start reduce of pre (consumed next iter)
        red = dpp_min32(pre);
        dm_prev = rdlane(dmv, b8 + u);      // dmin_tau
      }
    }
  }
  // epilogue: finalize a_{T-1} and flush last window
  float P = rdlane(red, 31);
  alpha = fminf(P, dm_prev + alpha);
  areg = (lane == 63) ? alpha : areg;
  alphaOut[(T_N - 64) + lane] = areg;
}

// ---------------- pass2: chunked warm-start replay per k (validated r1 == full-history r2) ----------------
#define CH 512
#define WARM 64
__global__ __launch_bounds__(256) void k_pass2(const float* __restrict__ d2,
                                               const float* __restrict__ AOUT,
                                               unsigned* __restrict__ pack) {
  int kb = blockIdx.x & 3;
  int tc = blockIdx.x >> 2;
  int k = kb * 256 + threadIdx.x;
  int ts = tc * CH;
  int start = ts - WARM; if (start < 0) start = 0;
  int end = ts + CH;
  __shared__ float lal[CH + WARM + 1];
  for (int i = threadIdx.x; i < end - start + 1; i += 256) {
    int idx = start - 1 + i;
    lal[i] = (idx < 0) ? 0.0f : AOUT[idx];
  }
  __syncthreads();
  float f = BIGF;
  unsigned s = 0;
#pragma unroll 4
  for (int tau = start; tau < end; ++tau) {
    float a_in = lal[tau - start];
    float d = d2[(size_t)tau * K_N + k];
    float ext = f - LMBDA;
    if (a_in < ext) s = (unsigned)tau;
    f = d + fminf(a_in, ext);
    if (tau >= ts) {
      float a_out = lal[tau - start + 1];
      if (f == a_out) atomicMin(&pack[tau], ((unsigned)k << 13) | s);
    }
  }
}

// ---------------- backtrack: ballot run-skip serial chase + parallel fill (validated r1) ----------------
__global__ __launch_bounds__(256) void k_backtrack(const unsigned* __restrict__ pack,
                                                   unsigned* __restrict__ unitsWs,
                                                   float* __restrict__ outUnits) {
  __shared__ unsigned lp[T_N];
  __shared__ unsigned long long msk[T_N / 64];
  int tid = threadIdx.x;
  for (int i = tid * 4; i < T_N; i += 1024) {
    *(uint4*)&lp[i] = *(const uint4*)&pack[i];
  }
  __syncthreads();
  if (tid < 64) {
    int lane = tid;
    int cur = T_N;
    for (int B = T_N - 64; B >= 0; B -= 64) {
      unsigned long long marks = 0ull;
      if (cur > B) {
        unsigned pk = lp[B + lane];
        int bv = (int)(pk & 8191u);
        unsigned long long run = __ballot(bv == B + lane);
        while (cur > B) {
          int L = cur - 1 - B;
          unsigned long long below = (L == 63) ? ~0ull : ((1ull << (L + 1)) - 1ull);
          unsigned long long nz = (~run) & below;
          if (nz == 0ull) { marks |= below; cur = B; break; }
          int j = 63 - __builtin_clzll(nz);
          marks |= below & ~((1ull << j) - 1ull);
          int nb = __builtin_amdgcn_readlane(bv, j);
          cur = nb;
          if (cur > B + j) cur = B + j;
        }
      }
      if (lane == 0) msk[B >> 6] = marks;
    }
  }
  __syncthreads();
  for (int p = tid; p < T_N; p += 256) {
    int w = p >> 6;
    unsigned long long m = msk[w] & (~0ull << (p & 63));
    while (m == 0ull) { ++w; m = msk[w]; }
    int idx = (w << 6) + (int)__builtin_ctzll(m);
    unsigned g = (lp[idx] >> 13) & 1023u;
    unitsWs[p] = g;
    outUnits[p] = (float)g;
  }
}

// ---------------- gather: quantized[t] = codebook[units[t]] ----------------
__global__ __launch_bounds__(256) void k_gather(const float* __restrict__ C,
                                                const unsigned* __restrict__ unitsWs,
                                                float* __restrict__ out) {
  int t = blockIdx.x;
  unsigned u = unitsWs[t] & 1023u;
  const float4* src = (const float4*)(C + (size_t)u * D_N);
  float4* dst = (float4*)(out + (size_t)t * D_N);
  dst[threadIdx.x] = src[threadIdx.x];
}

extern "C" void kernel_launch(void* const* d_in, const int* in_sizes, int n_in,
                              void* d_out, int out_size, void* d_ws, size_t ws_size,
                              hipStream_t stream) {
  const float* F = (const float*)d_in[0];
  const float* C = (const float*)d_in[1];
  float* out = (float*)d_out;
  float* d2 = out;                                  // reuse quantized region as d2 scratch
  float* outUnits = out + (size_t)T_N * D_N;
  char* ws = (char*)d_ws;
  float* alphaOut = (float*)(ws);                    // 32 KB
  unsigned* pack = (unsigned*)(ws + (32 << 10));     // 32 KB
  unsigned* unitsWs = (unsigned*)(ws + (64 << 10));  // 32 KB
  float* sf2 = (float*)(ws + (96 << 10));            // 32 KB
  float* sc2 = (float*)(ws + (128 << 10));           // 4 KB
  float* dminArr = (float*)(ws + (160 << 10));       // 32 KB
  int2* cand = (int2*)(ws + (1 << 20));              // 2 MB (8192 x 32 x 8B)
  int2* pd = (int2*)(ws + (3 << 20));                // 2 MB

  k_norms<<<(T_N + K_N) / 4, 256, 0, stream>>>(F, C, sf2, sc2);
  hipMemsetAsync(pack, 0xFF, T_N * sizeof(unsigned), stream);
  hipMemsetAsync(cand, 0xFF, (size_t)T_N * CMAX * sizeof(int2), stream);
  k_gemm<<<(T_N / 64) * (K_N / 64), 256, 0, stream>>>(F, C, sf2, sc2, d2);
  k_cand<<<T_N / 4, 256, 0, stream>>>(d2, cand, dminArr);
  k_prev<<<T_N / 4, 256, 0, stream>>>(cand, pd);
  k_pass1<<<1, 64, 0, stream>>>(pd, dminArr, alphaOut);
  k_pass2<<<(T_N / CH) * 4, 256, 0, stream>>>(d2, alphaOut, pack);
  k_backtrack<<<1, 256, 0, stream>>>(pack, unitsWs, outUnits);
  k_gather<<<T_N, 256, 0, stream>>>(C, unitsWs, out);
}

// Round 12
// 1050.822 us; speedup vs baseline: 3.5427x; 1.3067x over previous
//
#include <hip/hip_runtime.h>
#include <hip/hip_bf16.h>
#include <stdint.h>

#define T_N 8192
#define K_N 1024
#define D_N 1024
#define LMBDA 5.0f
#define BIGF 3.0e38f
#define CMAX 32
#define THR 26.0f      // 2*lambda + 4 bound + >10 ulp slack (r9-validated)
#define QNAN 0x7FC00000

// ---------------- norms: numpy-pairwise-exact sum of squares per row ----------------
__global__ __launch_bounds__(256) void k_norms(const float* __restrict__ F,
                                               const float* __restrict__ C,
                                               float* __restrict__ sf2,
                                               float* __restrict__ sc2) {
#pragma clang fp contract(off)
  int wave = threadIdx.x >> 6;
  int lane = threadIdx.x & 63;
  int row = blockIdx.x * 4 + wave;
  const float* src;
  float* dst;
  if (row < T_N) { src = F + (size_t)row * D_N; dst = sf2 + row; }
  else           { src = C + (size_t)(row - T_N) * D_N; dst = sc2 + (row - T_N); }
  int leaf = lane >> 3, j = lane & 7;
  const float* p = src + leaf * 128 + j;
  float x = p[0];
  float r = x * x;
#pragma unroll
  for (int i = 1; i < 16; ++i) {
    float y = p[8 * i];
    r = r + y * y;
  }
  r = r + __shfl_xor(r, 1, 64);
  r = r + __shfl_xor(r, 2, 64);
  r = r + __shfl_xor(r, 4, 64);
  r = r + __shfl_xor(r, 8, 64);
  r = r + __shfl_xor(r, 16, 64);
  r = r + __shfl_xor(r, 32, 64);
  if (lane == 0) *dst = r;
}

// ---------------- d2 GEMM: OpenBLAS-faithful f32 (numerics frozen — do not reorder) ----------------
__global__ __launch_bounds__(256) void k_gemm(const float* __restrict__ F,
                                              const float* __restrict__ C,
                                              const float* __restrict__ sf2,
                                              const float* __restrict__ sc2,
                                              float* __restrict__ d2) {
  __shared__ float As[32][68];
  __shared__ float Bs[32][68];
  int t0 = (int)(blockIdx.x >> 4) * 64;
  int k0 = (int)(blockIdx.x & 15) * 64;
  int tid = threadIdx.x;
  int tx = tid & 15, ty = tid >> 4;
  float acc[4][4], p0[4][4], p1[4][4];
#pragma unroll
  for (int i = 0; i < 4; ++i)
#pragma unroll
    for (int j = 0; j < 4; ++j) { acc[i][j] = 0.0f; p0[i][j] = 0.0f; p1[i][j] = 0.0f; }
  int r = tid & 63;
  int cbase = (tid >> 6) * 2;
  for (int d0 = 0; d0 < D_N; d0 += 32) {
    __syncthreads();
#pragma unroll
    for (int p = 0; p < 2; ++p) {
      int c4 = cbase + p;
      float4 va = *(const float4*)&F[(size_t)(t0 + r) * D_N + d0 + c4 * 4];
      As[c4 * 4 + 0][r] = va.x; As[c4 * 4 + 1][r] = va.y;
      As[c4 * 4 + 2][r] = va.z; As[c4 * 4 + 3][r] = va.w;
      float4 vb = *(const float4*)&C[(size_t)(k0 + r) * D_N + d0 + c4 * 4];
      Bs[c4 * 4 + 0][r] = vb.x; Bs[c4 * 4 + 1][r] = vb.y;
      Bs[c4 * 4 + 2][r] = vb.z; Bs[c4 * 4 + 3][r] = vb.w;
    }
    __syncthreads();
#pragma unroll
    for (int d = 0; d < 32; ++d) {
      float4 a = *(const float4*)&As[d][ty * 4];
      float4 b = *(const float4*)&Bs[d][tx * 4];
      acc[0][0] = fmaf(a.x, b.x, acc[0][0]); acc[0][1] = fmaf(a.x, b.y, acc[0][1]);
      acc[0][2] = fmaf(a.x, b.z, acc[0][2]); acc[0][3] = fmaf(a.x, b.w, acc[0][3]);
      acc[1][0] = fmaf(a.y, b.x, acc[1][0]); acc[1][1] = fmaf(a.y, b.y, acc[1][1]);
      acc[1][2] = fmaf(a.y, b.z, acc[1][2]); acc[1][3] = fmaf(a.y, b.w, acc[1][3]);
      acc[2][0] = fmaf(a.z, b.x, acc[2][0]); acc[2][1] = fmaf(a.z, b.y, acc[2][1]);
      acc[2][2] = fmaf(a.z, b.z, acc[2][2]); acc[2][3] = fmaf(a.z, b.w, acc[2][3]);
      acc[3][0] = fmaf(a.w, b.x, acc[3][0]); acc[3][1] = fmaf(a.w, b.y, acc[3][1]);
      acc[3][2] = fmaf(a.w, b.z, acc[3][2]); acc[3][3] = fmaf(a.w, b.w, acc[3][3]);
    }
    if (d0 == 352) {
#pragma unroll
      for (int i = 0; i < 4; ++i)
#pragma unroll
        for (int j = 0; j < 4; ++j) { p0[i][j] = acc[i][j]; acc[i][j] = 0.0f; }
    }
    if (d0 == 736) {
#pragma unroll
      for (int i = 0; i < 4; ++i)
#pragma unroll
        for (int j = 0; j < 4; ++j) { p1[i][j] = acc[i][j]; acc[i][j] = 0.0f; }
    }
  }
  {
#pragma clang fp contract(off)
#pragma unroll
    for (int i = 0; i < 4; ++i) {
      int t = t0 + ty * 4 + i;
      float sa = sf2[t];
      float o[4];
#pragma unroll
      for (int j = 0; j < 4; ++j) {
        float dot = (p0[i][j] + p1[i][j]) + acc[i][j];
        float two = 2.0f * dot;
        o[j] = (sa - two) + sc2[k0 + tx * 4 + j];
      }
      float4 ov; ov.x = o[0]; ov.y = o[1]; ov.z = o[2]; ov.w = o[3];
      *(float4*)&d2[(size_t)t * K_N + k0 + tx * 4] = ov;
    }
  }
}

// ---------------- cand: per row, candidate list {k: d <= dmin+THR} + row dmin ----------------
__global__ __launch_bounds__(256) void k_cand(const float* __restrict__ d2,
                                              int2* __restrict__ cand,
                                              float* __restrict__ dminOut) {
  int wave = threadIdx.x >> 6;
  int lane = threadIdx.x & 63;
  int row = blockIdx.x * 4 + wave;
  const float4* p = (const float4*)(d2 + (size_t)row * K_N + lane * 16);
  float4 v0 = p[0], v1 = p[1], v2 = p[2], v3 = p[3];
  float m = fminf(fminf(fminf(v0.x, v0.y), fminf(v0.z, v0.w)),
                  fminf(fminf(v1.x, v1.y), fminf(v1.z, v1.w)));
  float n = fminf(fminf(fminf(v2.x, v2.y), fminf(v2.z, v2.w)),
                  fminf(fminf(v3.x, v3.y), fminf(v3.z, v3.w)));
  m = fminf(m, n);
  m = fminf(m, __shfl_xor(m, 1, 64));
  m = fminf(m, __shfl_xor(m, 2, 64));
  m = fminf(m, __shfl_xor(m, 4, 64));
  m = fminf(m, __shfl_xor(m, 8, 64));
  m = fminf(m, __shfl_xor(m, 16, 64));
  m = fminf(m, __shfl_xor(m, 32, 64));
  if (lane == 0) dminOut[row] = m;
  float thr = m + THR;
  unsigned flags = 0;
#define TESTC(J, VAL) if ((VAL) <= thr) flags |= (1u << (J));
  TESTC(0, v0.x) TESTC(1, v0.y) TESTC(2, v0.z) TESTC(3, v0.w)
  TESTC(4, v1.x) TESTC(5, v1.y) TESTC(6, v1.z) TESTC(7, v1.w)
  TESTC(8, v2.x) TESTC(9, v2.y) TESTC(10, v2.z) TESTC(11, v2.w)
  TESTC(12, v3.x) TESTC(13, v3.y) TESTC(14, v3.z) TESTC(15, v3.w)
#undef TESTC
  int c = __popc(flags);
  int pre = c;
#pragma unroll
  for (int off = 1; off <= 32; off <<= 1) {
    int t = __shfl_up(pre, off, 64);
    if (lane >= off) pre += t;
  }
  int idx = pre - c;
  int2* rowp = cand + (size_t)row * CMAX;
  int kb = lane * 16;
#define EMITC(J, VAL)                                                        \
  if (flags & (1u << (J))) {                                                 \
    if (idx < CMAX) rowp[idx] = make_int2(kb + (J), __float_as_int(VAL));    \
    ++idx;                                                                   \
  }
  EMITC(0, v0.x) EMITC(1, v0.y) EMITC(2, v0.z) EMITC(3, v0.w)
  EMITC(4, v1.x) EMITC(5, v1.y) EMITC(6, v1.z) EMITC(7, v1.w)
  EMITC(8, v2.x) EMITC(9, v2.y) EMITC(10, v2.z) EMITC(11, v2.w)
  EMITC(12, v3.x) EMITC(13, v3.y) EMITC(14, v3.z) EMITC(15, v3.w)
#undef EMITC
}

// ---------------- prev2: per-pair lane data for the G=2 pass1 ----------------
// pair p (t0=2p, t1=2p+1):
//  lane<32 (slot j of t1):  (pp2, d0bits) — pp2 = byteaddr of k_j in S_{2p-1} list
//      (valid only if k_j ∈ S_t0, else -4); d0 = d_t0[k_j] or NaN if k_j ∉ S_t0.
//  lane>=32 (slot i of t0): (pp, d0bits) — pp = byteaddr of k_i in S_{2p-1}; d0 = d_t0[k_i].
__global__ __launch_bounds__(256) void k_prev2(const int2* __restrict__ cand,
                                               int2* __restrict__ pairbuf) {
  __shared__ int km1[4][32];
  __shared__ int kt0[4][32];
  __shared__ int dt0[4][32];
  int w = threadIdx.x >> 6, lane = threadIdx.x & 63;
  int p = blockIdx.x * 4 + w;
  int t0 = 2 * p, t1 = 2 * p + 1, tm1 = t0 - 1;
  if (lane < 32) {
    int2 c0 = cand[(size_t)t0 * CMAX + lane];
    kt0[w][lane] = c0.x; dt0[w][lane] = c0.y;
  } else {
    int j = lane - 32;
    km1[w][j] = (p > 0) ? cand[(size_t)tm1 * CMAX + j].x : -2;
  }
  __syncthreads();
  int2 out;
  if (lane < 32) {
    int2 c1 = cand[(size_t)t1 * CMAX + lane];
    int k1 = c1.x;
    int pp2 = -4, d0 = QNAN;
    bool in0 = false;
#pragma unroll
    for (int i = 0; i < 32; ++i) if (kt0[w][i] == k1) { d0 = dt0[w][i]; in0 = true; }
#pragma unroll
    for (int i = 0; i < 32; ++i) if (km1[w][i] == k1) pp2 = i * 4;
    if (!in0 || k1 < 0) { pp2 = -4; d0 = (k1 < 0 || !in0) ? QNAN : d0; }
    out = make_int2(pp2, d0);
  } else {
    int i0 = lane - 32;
    int k0 = kt0[w][i0];
    int d0 = dt0[w][i0];
    int pp = -4;
#pragma unroll
    for (int i = 0; i < 32; ++i) if (km1[w][i] == k0) pp = i * 4;
    if (k0 < 0) pp = -4;   // sentinel slot (d0 already NaN)
    out = make_int2(pp, d0);
  }
  pairbuf[(size_t)p * 64 + lane] = out;
}

// ---------------- DPP min per 32-lane half (lane 31: lower half; lane 63: upper half) --------
__device__ __forceinline__ float dpp_min32(float x) {
  int t;
  t = __builtin_amdgcn_update_dpp(__float_as_int(x), __float_as_int(x), 0x111, 0xF, 0xF, false);
  x = fminf(x, __int_as_float(t));
  t = __builtin_amdgcn_update_dpp(__float_as_int(x), __float_as_int(x), 0x112, 0xF, 0xF, false);
  x = fminf(x, __int_as_float(t));
  t = __builtin_amdgcn_update_dpp(__float_as_int(x), __float_as_int(x), 0x114, 0xF, 0xF, false);
  x = fminf(x, __int_as_float(t));
  t = __builtin_amdgcn_update_dpp(__float_as_int(x), __float_as_int(x), 0x118, 0xF, 0xF, false);
  x = fminf(x, __int_as_float(t));
  t = __builtin_amdgcn_update_dpp(__float_as_int(x), __float_as_int(x), 0x142, 0xF, 0xF, false); // row_bcast:15
  x = fminf(x, __int_as_float(t));
  return x;
}
__device__ __forceinline__ float rdlane(float x, int l) {
  return __int_as_float(__builtin_amdgcn_readlane(__float_as_int(x), l));
}

// ---------------- pass1: G=2 sparse alpha chain — ONE bpermute per TWO rows ----------------
// lanes 32-63: pre_t0 = d0 + (fp - L)            (row 2p candidates)
// lanes  0-31: A0 = d0+(fp2-L); A1 = d1+(A0-L); B0 = d0+a_{2p-1}; B1 = d1+(B0-L)
// a_2p   = min(P_pre0, dmin_2p + a_{2p-1})       (P_pre0 = lane-63 reduce, consumed now)
// f_t1   = min(A1, B1, d1 + a_2p)   -> carried fstate (lanes 0-31)
// a_2p+1 = min(P_AB1, dmin_2p+1 + a_2p)          (P_AB1 = lane-31 reduce, consumed NEXT pair)
// All identities exact on the f32 lattice (r6/r8/r9/r10-validated pieces).
__global__ __launch_bounds__(64, 1) void k_pass1(const int2* __restrict__ pairbuf,
                                                 const int2* __restrict__ cand,
                                                 const float* __restrict__ dminArr,
                                                 float* __restrict__ alphaOut) {
  const int lane = threadIdx.x;
  const int2* basep = pairbuf + lane;
  const int2* basec = cand + (lane & 31);
  int2 rg[8], rgc[8];
#pragma unroll
  for (int u = 0; u < 8; ++u) {
    rg[u] = basep[(size_t)u * 64];
    rgc[u] = basec[(size_t)(2 * u + 1) * CMAX];
  }
  float fstate = BIGF;      // f_{2p-1} at lanes 0-31
  float alpha = 0.0f;       // after finalize: a_{2p-1}; after pair body: a_{2p}
  float redAB = 0.0f;       // pending lane-31 reduce (P_AB1 of previous pair)
  float dmT1prev = 0.0f;    // dmin_{2p-1}
  float areg = 0.0f;
  float dmv_next = dminArr[lane];
  const int NP = T_N / 2;
  for (int pb32 = 0; pb32 < NP; pb32 += 32) {     // 32 pairs = 64 rows per dmv block
    float dmv = dmv_next;
    int nb = pb32 + 32; if (nb >= NP) nb = 0;
    dmv_next = dminArr[2 * nb + lane];
    for (int pb8 = 0; pb8 < 32; pb8 += 8) {
#pragma unroll
      for (int u = 0; u < 8; ++u) {
        int p = pb32 + pb8 + u;
        int2 pv = rg[u];
        int2 cv = rgc[u];
        // issue the pair's single bpermute first (longest latency)
        int fpb = __builtin_amdgcn_ds_bpermute(pv.x, __float_as_int(fstate));
        // prefetch pair p+8
        int pn = p + 8; if (pn > NP - 1) pn = NP - 1;
        rg[u] = basep[(size_t)pn * 64];
        rgc[u] = basec[(size_t)(2 * pn + 1) * CMAX];
        // finalize a_{2p-1} (overlaps bpermute)
        float Pab = rdlane(redAB, 31);
        alpha = fminf(Pab, dmT1prev + alpha);
        int posA = 2 * p - 1;
        if (posA >= 0) {
          areg = ((posA & 63) == lane) ? alpha : areg;
          if ((posA & 63) == 63) alphaOut[(posA & ~63) + lane] = areg;
        }
        int r0 = 2 * (pb8 + u);
        float dm0 = rdlane(dmv, r0);
        float dm1 = rdlane(dmv, r0 + 1);
        // pair computation
        float fp = (pv.x < 0) ? BIGF : __int_as_float(fpb);
        float d0 = __int_as_float(pv.y);
        float d1 = __int_as_float(cv.y);
        float v0 = d0 + (fp - LMBDA);        // lanes<32: A0 ; lanes>=32: pre_t0
        float A1 = d1 + (v0 - LMBDA);
        float B0 = d0 + alpha;
        float B1 = d1 + (B0 - LMBDA);
        float mab = fminf(A1, B1);
        float x = (lane < 32) ? mab : v0;
        float red = dpp_min32(x);
        float Pp0 = rdlane(red, 63);         // min pre_t0 over t0 slots
        float a0 = fminf(Pp0, dm0 + alpha);  // a_{2p}
        areg = (((2 * p) & 63) == lane) ? a0 : areg;   // even pos: never flushes
        fstate = fminf(mab, d1 + a0);        // f_{2p+1}
        redAB = red;                          // lane 31 = P_AB1, consumed next pair
        dmT1prev = dm1;
        alpha = a0;
      }
    }
  }
  // epilogue: a_{T-1}
  float Pab = rdlane(redAB, 31);
  alpha = fminf(Pab, dmT1prev + alpha);
  areg = (lane == 63) ? alpha : areg;
  alphaOut[(T_N - 64) + lane] = areg;
}

// ---------------- pass2: chunked warm-start replay per k (validated r1 == full-history r2) ----------------
#define CH 512
#define WARM 64
__global__ __launch_bounds__(256) void k_pass2(const float* __restrict__ d2,
                                               const float* __restrict__ AOUT,
                                               unsigned* __restrict__ pack) {
  int kb = blockIdx.x & 3;
  int tc = blockIdx.x >> 2;
  int k = kb * 256 + threadIdx.x;
  int ts = tc * CH;
  int start = ts - WARM; if (start < 0) start = 0;
  int end = ts + CH;
  __shared__ float lal[CH + WARM + 1];
  for (int i = threadIdx.x; i < end - start + 1; i += 256) {
    int idx = start - 1 + i;
    lal[i] = (idx < 0) ? 0.0f : AOUT[idx];
  }
  __syncthreads();
  float f = BIGF;
  unsigned s = 0;
#pragma unroll 4
  for (int tau = start; tau < end; ++tau) {
    float a_in = lal[tau - start];
    float d = d2[(size_t)tau * K_N + k];
    float ext = f - LMBDA;
    if (a_in < ext) s = (unsigned)tau;
    f = d + fminf(a_in, ext);
    if (tau >= ts) {
      float a_out = lal[tau - start + 1];
      if (f == a_out) atomicMin(&pack[tau], ((unsigned)k << 13) | s);
    }
  }
}

// ---------------- backtrack: ballot run-skip serial chase + parallel fill (validated r1) ----------------
__global__ __launch_bounds__(256) void k_backtrack(const unsigned* __restrict__ pack,
                                                   unsigned* __restrict__ unitsWs,
                                                   float* __restrict__ outUnits) {
  __shared__ unsigned lp[T_N];
  __shared__ unsigned long long msk[T_N / 64];
  int tid = threadIdx.x;
  for (int i = tid * 4; i < T_N; i += 1024) {
    *(uint4*)&lp[i] = *(const uint4*)&pack[i];
  }
  __syncthreads();
  if (tid < 64) {
    int lane = tid;
    int cur = T_N;
    for (int B = T_N - 64; B >= 0; B -= 64) {
      unsigned long long marks = 0ull;
      if (cur > B) {
        unsigned pk = lp[B + lane];
        int bv = (int)(pk & 8191u);
        unsigned long long run = __ballot(bv == B + lane);
        while (cur > B) {
          int L = cur - 1 - B;
          unsigned long long below = (L == 63) ? ~0ull : ((1ull << (L + 1)) - 1ull);
          unsigned long long nz = (~run) & below;
          if (nz == 0ull) { marks |= below; cur = B; break; }
          int j = 63 - __builtin_clzll(nz);
          marks |= below & ~((1ull << j) - 1ull);
          int nb = __builtin_amdgcn_readlane(bv, j);
          cur = nb;
          if (cur > B + j) cur = B + j;
        }
      }
      if (lane == 0) msk[B >> 6] = marks;
    }
  }
  __syncthreads();
  for (int p = tid; p < T_N; p += 256) {
    int w = p >> 6;
    unsigned long long m = msk[w] & (~0ull << (p & 63));
    while (m == 0ull) { ++w; m = msk[w]; }
    int idx = (w << 6) + (int)__builtin_ctzll(m);
    unsigned g = (lp[idx] >> 13) & 1023u;
    unitsWs[p] = g;
    outUnits[p] = (float)g;
  }
}

// ---------------- gather: quantized[t] = codebook[units[t]] ----------------
__global__ __launch_bounds__(256) void k_gather(const float* __restrict__ C,
                                                const unsigned* __restrict__ unitsWs,
                                                float* __restrict__ out) {
  int t = blockIdx.x;
  unsigned u = unitsWs[t] & 1023u;
  const float4* src = (const float4*)(C + (size_t)u * D_N);
  float4* dst = (float4*)(out + (size_t)t * D_N);
  dst[threadIdx.x] = src[threadIdx.x];
}

extern "C" void kernel_launch(void* const* d_in, const int* in_sizes, int n_in,
                              void* d_out, int out_size, void* d_ws, size_t ws_size,
                              hipStream_t stream) {
  const float* F = (const float*)d_in[0];
  const float* C = (const float*)d_in[1];
  float* out = (float*)d_out;
  float* d2 = out;                                  // reuse quantized region as d2 scratch
  float* outUnits = out + (size_t)T_N * D_N;
  char* ws = (char*)d_ws;
  float* alphaOut = (float*)(ws);                    // 32 KB
  unsigned* pack = (unsigned*)(ws + (32 << 10));     // 32 KB
  unsigned* unitsWs = (unsigned*)(ws + (64 << 10));  // 32 KB
  float* sf2 = (float*)(ws + (96 << 10));            // 32 KB
  float* sc2 = (float*)(ws + (128 << 10));           // 4 KB
  float* dminArr = (float*)(ws + (160 << 10));       // 32 KB
  int2* cand = (int2*)(ws + (1 << 20));              // 2 MB (8192 x 32 x 8B)
  int2* pairbuf = (int2*)(ws + (3 << 20));           // 2 MB (4096 x 64 x 8B)

  k_norms<<<(T_N + K_N) / 4, 256, 0, stream>>>(F, C, sf2, sc2);
  hipMemsetAsync(pack, 0xFF, T_N * sizeof(unsigned), stream);
  hipMemsetAsync(cand, 0xFF, (size_t)T_N * CMAX * sizeof(int2), stream);
  k_gemm<<<(T_N / 64) * (K_N / 64), 256, 0, stream>>>(F, C, sf2, sc2, d2);
  k_cand<<<T_N / 4, 256, 0, stream>>>(d2, cand, dminArr);
  k_prev2<<<(T_N / 2) / 4, 256, 0, stream>>>(cand, pairbuf);
  k_pass1<<<1, 64, 0, stream>>>(pairbuf, cand, dminArr, alphaOut);
  k_pass2<<<(T_N / CH) * 4, 256, 0, stream>>>(d2, alphaOut, pack);
  k_backtrack<<<1, 256, 0, stream>>>(pack, unitsWs, outUnits);
  k_gather<<<T_N, 256, 0, stream>>>(C, unitsWs, out);
}